// Round 7
// baseline (730.813 us; speedup 1.0000x reference)
//
#include <hip/hip_runtime.h>
#include <hip/hip_bf16.h>
#include <math.h>

typedef unsigned short u16;
typedef unsigned int u32;
typedef __attribute__((ext_vector_type(8))) short bf16x8;
typedef __attribute__((ext_vector_type(4))) float f32x4;

__device__ __forceinline__ u16 f2b(float f) {
    union { float f; unsigned u; } v; v.f = f;
    unsigned r = v.u + 0x7fffu + ((v.u >> 16) & 1u);
    return (u16)(r >> 16);
}
__device__ __forceinline__ float b2f(u16 h) {
    union { unsigned u; float f; } v; v.u = ((unsigned)h) << 16; return v.f;
}

// global -> LDS direct DMA, 16 bytes per lane. LDS dest = uniform base + lane*16.
__device__ __forceinline__ void gld16(const u16* gp, u16* lp) {
    auto g = (const __attribute__((address_space(1))) u32*)gp;
    auto l = (__attribute__((address_space(3))) u32*)lp;
    __builtin_amdgcn_global_load_lds(g, l, 16, 0, 0);
}

// Conflict-free layout (R4/R6-verified, 0 conflicts): subtile row = 32 u16 (64 B),
// four 16B blocks; physical block for logical block q at row r: (q+(r>>1))&3.
__device__ __forceinline__ int swz4(int row, int q) { return (q + (row >> 1)) & 3; }

// ---------------------------------------------------------------------------
// bf16 MFMA GEMM, double-buffered LDS, prefetch-past-barrier, BK=64.
// C = alpha * A @ Bt^T (+bias) (+res). A: MxK (lda), Bt: NxK (ldb), bf16.
// K % 64 == 0. N-tile 128. M-tile = MT. One barrier per K-step.
// OOB M rows DMA garbage from within ws (store-guarded); keep guard region.
// ---------------------------------------------------------------------------
struct GemmP {
    const u16* A; const u16* B;
    const float* bias; const float* res;
    float* Cf; u16* Cb;
    int M, N, K, lda, ldb, ldc;
    float alpha;
};

template<int MT>
__global__ __launch_bounds__(256) void gemm_bt(GemmP p) {
    constexpr int MI = MT / 32;
    __shared__ u16 As[2][MT * 64];    // [buf][sub(2)][MT][32]
    __shared__ u16 Bs[2][128 * 64];   // [buf][sub(2)][128][32]
    const int tid = threadIdx.x;
    const int m0 = blockIdx.y * MT, n0 = blockIdx.x * 128;
    const int lane = tid & 63, wave = tid >> 6;
    const int quad = lane >> 4, l16 = lane & 15;
    const int wr = (wave >> 1) * (MT / 2), wc = (wave & 1) * 64;
    const int srow4 = lane >> 2, pcb4 = lane & 3;

    f32x4 acc[MI][4];
#pragma unroll
    for (int i = 0; i < MI; i++)
#pragma unroll
        for (int j = 0; j < 4; j++) acc[i][j] = (f32x4){0.f, 0.f, 0.f, 0.f};

    auto stage = [&](int buf, int k0) {
#pragma unroll
        for (int c = 0; c < MT / 32; c++) {
            int cc = wave * (MT / 32) + c;
            int sub = cc / (MT / 16), rg = cc % (MT / 16);
            int r = rg * 16 + srow4;
            int lcb = (pcb4 - (r >> 1)) & 3;
            gld16(p.A + (long)(m0 + r) * p.lda + k0 + sub * 32 + lcb * 8,
                  &As[buf][sub * (MT * 32) + rg * 512]);
        }
#pragma unroll
        for (int c = 0; c < 4; c++) {
            int cc = wave * 4 + c;
            int sub = cc >> 3, rg = cc & 7;
            int r = rg * 16 + srow4;
            int lcb = (pcb4 - (r >> 1)) & 3;
            gld16(p.B + (long)(n0 + r) * p.ldb + k0 + sub * 32 + lcb * 8,
                  &Bs[buf][sub * 4096 + rg * 512]);
        }
    };

    const int nIter = p.K >> 6;
    stage(0, 0);
    int buf = 0;
    for (int it = 0; it < nIter; it++) {
        __syncthreads();
        if (it + 1 < nIter) stage(buf ^ 1, (it + 1) << 6);
#pragma unroll
        for (int sub = 0; sub < 2; sub++) {
            bf16x8 af[MI], bfr[4];
#pragma unroll
            for (int mi = 0; mi < MI; mi++) {
                int row = wr + mi * 16 + l16;
                af[mi] = *(const bf16x8*)&As[buf][sub * (MT * 32) + row * 32 + swz4(row, quad) * 8];
            }
#pragma unroll
            for (int ni = 0; ni < 4; ni++) {
                int row = wc + ni * 16 + l16;
                bfr[ni] = *(const bf16x8*)&Bs[buf][sub * 4096 + row * 32 + swz4(row, quad) * 8];
            }
#pragma unroll
            for (int mi = 0; mi < MI; mi++)
#pragma unroll
                for (int ni = 0; ni < 4; ni++)
                    acc[mi][ni] = __builtin_amdgcn_mfma_f32_16x16x32_bf16(af[mi], bfr[ni], acc[mi][ni], 0, 0, 0);
        }
        buf ^= 1;
    }

#pragma unroll
    for (int mi = 0; mi < MI; mi++) {
#pragma unroll
        for (int ni = 0; ni < 4; ni++) {
#pragma unroll
            for (int r = 0; r < 4; r++) {
                int row = m0 + wr + mi * 16 + quad * 4 + r;
                int col = n0 + wc + ni * 16 + l16;
                if (row < p.M && col < p.N) {
                    float v = acc[mi][ni][r] * p.alpha;
                    if (p.bias) v += p.bias[col];
                    long idx = (long)row * p.ldc + col;
                    if (p.res) v += p.res[idx];
                    if (p.Cf) p.Cf[idx] = v; else p.Cb[idx] = f2b(v);
                }
            }
        }
    }
}

// ---------------------------------------------------------------------------
// Fused ff1 + GEGLU, double-buffered BK=32, prefetch-past-barrier.
// XCD n-ownership grid: (x=8, y=M/128, z=3); n_tile = z*8+x (skip >=20).
// id%8 == x -> XCD x owns n-tiles {x, x+8, x+16}: its <=1MB of W stays
// L2-resident across the whole m-sweep; A re-reads hit L3.
// ---------------------------------------------------------------------------
struct GegluP {
    const u16* A; const u16* Bx; const u16* Bg;
    const float* bx; const float* bg;
    u16* H;
    int K, lda, ldb, ldh;
};

__global__ __launch_bounds__(256) void gemm_geglu(GegluP p) {
    __shared__ u16 As[2][128 * 32];
    __shared__ u16 Bxs[2][128 * 32];
    __shared__ u16 Bgs[2][128 * 32];
    const int n_t = blockIdx.z * 8 + blockIdx.x;
    if (n_t >= 20) return;
    const int tid = threadIdx.x;
    const int m0 = blockIdx.y * 128, n0 = n_t * 128;
    const int lane = tid & 63, wave = tid >> 6;
    const int quad = lane >> 4, l16 = lane & 15;
    const int wr = (wave >> 1) * 64, wc = (wave & 1) * 64;
    const int srow4 = lane >> 2, pcb4 = lane & 3;

    f32x4 ax[4][4], ag[4][4];
#pragma unroll
    for (int i = 0; i < 4; i++)
#pragma unroll
        for (int j = 0; j < 4; j++) { ax[i][j] = (f32x4){0.f,0.f,0.f,0.f}; ag[i][j] = (f32x4){0.f,0.f,0.f,0.f}; }

    auto stage = [&](int buf, int k0) {
#pragma unroll
        for (int c = 0; c < 2; c++) {
            int rg = wave * 2 + c;
            int r = rg * 16 + srow4;
            int lcb = (pcb4 - (r >> 1)) & 3;
            gld16(p.A  + (long)(m0 + r) * p.lda + k0 + lcb * 8, &As[buf][rg * 512]);
            gld16(p.Bx + (long)(n0 + r) * p.ldb + k0 + lcb * 8, &Bxs[buf][rg * 512]);
            gld16(p.Bg + (long)(n0 + r) * p.ldb + k0 + lcb * 8, &Bgs[buf][rg * 512]);
        }
    };

    const int nIter = p.K >> 5;
    stage(0, 0);
    int buf = 0;
    for (int it = 0; it < nIter; it++) {
        __syncthreads();
        if (it + 1 < nIter) stage(buf ^ 1, (it + 1) << 5);
        bf16x8 af[4], bxf[4], bgf[4];
#pragma unroll
        for (int mi = 0; mi < 4; mi++) {
            int row = wr + mi * 16 + l16;
            af[mi] = *(const bf16x8*)&As[buf][row * 32 + swz4(row, quad) * 8];
        }
#pragma unroll
        for (int ni = 0; ni < 4; ni++) {
            int row = wc + ni * 16 + l16;
            bxf[ni] = *(const bf16x8*)&Bxs[buf][row * 32 + swz4(row, quad) * 8];
            bgf[ni] = *(const bf16x8*)&Bgs[buf][row * 32 + swz4(row, quad) * 8];
        }
#pragma unroll
        for (int mi = 0; mi < 4; mi++)
#pragma unroll
            for (int ni = 0; ni < 4; ni++) {
                ax[mi][ni] = __builtin_amdgcn_mfma_f32_16x16x32_bf16(af[mi], bxf[ni], ax[mi][ni], 0, 0, 0);
                ag[mi][ni] = __builtin_amdgcn_mfma_f32_16x16x32_bf16(af[mi], bgf[ni], ag[mi][ni], 0, 0, 0);
            }
        buf ^= 1;
    }

#pragma unroll
    for (int mi = 0; mi < 4; mi++) {
#pragma unroll
        for (int ni = 0; ni < 4; ni++) {
#pragma unroll
            for (int r = 0; r < 4; r++) {
                int row = m0 + wr + mi * 16 + quad * 4 + r;
                int col = wc + ni * 16 + l16;
                float xh = ax[mi][ni][r] + p.bx[n0 + col];
                float g  = ag[mi][ni][r] + p.bg[n0 + col];
                float u  = 0.7978845608f * g * (1.0f + 0.044715f * g * g);
                float s  = 1.0f / (1.0f + __expf(-2.0f * u));
                p.H[(long)row * p.ldh + n0 + col] = f2b(xh * g * s);
            }
        }
    }
}

// ---------------------------------------------------------------------------
// Fused flash attention. Grid: (64 heads, 1, nQtiles); blockIdx.x = z = b*8+h
// -> q-tile blocks of one head share an XCD -> K/V served from that XCD's L2.
// Scale is folded into Q at staging; full K-tiles take the maskless fast path.
// ---------------------------------------------------------------------------
struct FlashP {
    const u16* Q; const u16* K; const u16* V;
    u16* O;
    int ldq, ldk, ldv, ldo;
    int S, TS, nIter;
    long qBatch, kBatch;
    float scale;
};

__global__ __launch_bounds__(256, 2) void flash_attn(FlashP p) {
    __shared__ u16 shU[128 * 136];
    __shared__ u16 shV[80 * 136];
    const int z = blockIdx.x, b = z >> 3, h = z & 7;
    const int q0 = blockIdx.z * 128;
    const int tid = threadIdx.x, lane = tid & 63, w = tid >> 6;
    const int quad = lane >> 4, l16 = lane & 15;

    const u16* Qp = p.Q + (long)b * p.qBatch + (long)q0 * p.ldq + h * 80;
    const u16* Kp = p.K + (long)b * p.kBatch + h * 80;
    const u16* Vp = p.V + (long)b * p.kBatch + h * 80;

    // stage Q (pre-scaled by p.scale)
    for (int idx = tid; idx < 128 * 12; idx += 256) {
        int row = idx / 12, g = idx - row * 12;
        uint4 v = {0, 0, 0, 0};
        if (g < 10) {
            v = *(const uint4*)(Qp + (long)row * p.ldq + g * 8);
            u16 tmp[8]; *(uint4*)tmp = v;
#pragma unroll
            for (int j = 0; j < 8; j++) tmp[j] = f2b(b2f(tmp[j]) * p.scale);
            v = *(uint4*)tmp;
        }
        *(uint4*)&shU[row * 104 + g * 8] = v;
    }
    __syncthreads();
    bf16x8 qf[2][3];
#pragma unroll
    for (int mi = 0; mi < 2; mi++)
#pragma unroll
        for (int kk = 0; kk < 3; kk++)
            qf[mi][kk] = *(const bf16x8*)&shU[(w * 32 + mi * 16 + l16) * 104 + kk * 32 + quad * 8];
    __syncthreads();

    float m_[2][4], l_[2][4];
    f32x4 acc_o[2][5];
#pragma unroll
    for (int mi = 0; mi < 2; mi++) {
#pragma unroll
        for (int r = 0; r < 4; r++) { m_[mi][r] = -1e30f; l_[mi][r] = 0.f; }
#pragma unroll
        for (int ni = 0; ni < 5; ni++) acc_o[mi][ni] = (f32x4){0.f, 0.f, 0.f, 0.f};
    }

    for (int it = 0; it < p.nIter; it++) {
        const int s0 = it * 128;
        const bool full = (s0 + 128 <= p.TS);
        for (int idx = tid; idx < 128 * 12; idx += 256) {
            int row = idx / 12, g = idx - row * 12;
            uint4 v = {0, 0, 0, 0};
            if (g < 10 && (s0 + row) < p.TS)
                v = *(const uint4*)(Kp + (long)(s0 + row) * p.ldk + g * 8);
            *(uint4*)&shU[row * 104 + g * 8] = v;
        }
        for (int idx = tid; idx < 128 * 10; idx += 256) {
            int row = idx / 10, g = idx - row * 10;
            uint4 v = {0, 0, 0, 0};
            if ((s0 + row) < p.TS)
                v = *(const uint4*)(Vp + (long)(s0 + row) * p.ldv + g * 8);
            u16 tmp[8]; *(uint4*)tmp = v;
#pragma unroll
            for (int j = 0; j < 8; j++) shV[(g * 8 + j) * 136 + row] = tmp[j];
        }
        __syncthreads();

        f32x4 acc_s[2][8];
#pragma unroll
        for (int mi = 0; mi < 2; mi++)
#pragma unroll
            for (int ni = 0; ni < 8; ni++) acc_s[mi][ni] = (f32x4){0.f, 0.f, 0.f, 0.f};
#pragma unroll
        for (int kk = 0; kk < 3; kk++) {
            bf16x8 kf[8];
#pragma unroll
            for (int ni = 0; ni < 8; ni++)
                kf[ni] = *(const bf16x8*)&shU[(ni * 16 + l16) * 104 + kk * 32 + quad * 8];
#pragma unroll
            for (int mi = 0; mi < 2; mi++)
#pragma unroll
                for (int ni = 0; ni < 8; ni++)
                    acc_s[mi][ni] = __builtin_amdgcn_mfma_f32_16x16x32_bf16(qf[mi][kk], kf[ni], acc_s[mi][ni], 0, 0, 0);
        }
        __syncthreads();

        if (!full) {
#pragma unroll
            for (int mi = 0; mi < 2; mi++)
#pragma unroll
                for (int ni = 0; ni < 8; ni++) {
                    bool valid = (s0 + ni * 16 + l16) < p.TS;
#pragma unroll
                    for (int r = 0; r < 4; r++)
                        if (!valid) acc_s[mi][ni][r] = -1e30f;
                }
        }
#pragma unroll
        for (int mi = 0; mi < 2; mi++) {
#pragma unroll
            for (int r = 0; r < 4; r++) {
                float rm = acc_s[mi][0][r];
#pragma unroll
                for (int ni = 1; ni < 8; ni++) rm = fmaxf(rm, acc_s[mi][ni][r]);
#pragma unroll
                for (int msk = 1; msk < 16; msk <<= 1) rm = fmaxf(rm, __shfl_xor(rm, msk));
                float mn = fmaxf(m_[mi][r], rm);
                float al = __expf(m_[mi][r] - mn);
                m_[mi][r] = mn;
                float rs = 0.f;
                int prow = (w * 32 + mi * 16 + quad * 4 + r) * 136;
#pragma unroll
                for (int ni = 0; ni < 8; ni++) {
                    float pv = __expf(acc_s[mi][ni][r] - mn);
                    rs += pv;
                    shU[prow + ni * 16 + l16] = f2b(pv);
                }
#pragma unroll
                for (int msk = 1; msk < 16; msk <<= 1) rs += __shfl_xor(rs, msk);
                l_[mi][r] = l_[mi][r] * al + rs;
#pragma unroll
                for (int ni = 0; ni < 5; ni++) acc_o[mi][ni][r] *= al;
            }
        }
        __syncthreads();

#pragma unroll
        for (int kk = 0; kk < 4; kk++) {
            bf16x8 vf[5], pf[2];
#pragma unroll
            for (int ni = 0; ni < 5; ni++)
                vf[ni] = *(const bf16x8*)&shV[(ni * 16 + l16) * 136 + kk * 32 + quad * 8];
#pragma unroll
            for (int mi = 0; mi < 2; mi++)
                pf[mi] = *(const bf16x8*)&shU[(w * 32 + mi * 16 + l16) * 136 + kk * 32 + quad * 8];
#pragma unroll
            for (int mi = 0; mi < 2; mi++)
#pragma unroll
                for (int ni = 0; ni < 5; ni++)
                    acc_o[mi][ni] = __builtin_amdgcn_mfma_f32_16x16x32_bf16(pf[mi], vf[ni], acc_o[mi][ni], 0, 0, 0);
        }
        __syncthreads();
    }

    u16* Op = p.O + ((long)b * p.S + q0) * p.ldo + h * 80;
#pragma unroll
    for (int mi = 0; mi < 2; mi++) {
#pragma unroll
        for (int r = 0; r < 4; r++) {
            float inv = 1.0f / l_[mi][r];
            int row = w * 32 + mi * 16 + quad * 4 + r;
#pragma unroll
            for (int ni = 0; ni < 5; ni++)
                Op[(long)row * p.ldo + ni * 16 + l16] = f2b(acc_o[mi][ni][r] * inv);
        }
    }
}

// ---------------------------------------------------------------------------
struct WT8 { const float* W[8]; u16* Wt[8]; };

__global__ void wtrans8(WT8 p, int K, int N) {
    __shared__ float tile[32][33];
    const float* W = p.W[blockIdx.z];
    u16* Wt = p.Wt[blockIdx.z];
    int n0 = blockIdx.x * 32, k0 = blockIdx.y * 32;
    int tx = threadIdx.x, ty = threadIdx.y;
#pragma unroll
    for (int i = 0; i < 4; i++) {
        int k = k0 + ty + i * 8, n = n0 + tx;
        if (k < K && n < N) tile[ty + i * 8][tx] = W[(long)k * N + n];
    }
    __syncthreads();
#pragma unroll
    for (int i = 0; i < 4; i++) {
        int n = n0 + ty + i * 8, k = k0 + tx;
        if (n < N && k < K) Wt[(long)n * K + k] = f2b(tile[tx][ty + i * 8]);
    }
}

// ---------------------------------------------------------------------------
__global__ void gn_stats(const float* __restrict__ x, float* __restrict__ stats) {
    int bid = blockIdx.x;
    int b = bid >> 5, g = bid & 31;
    const float* base = x + (long)b * 32 * 32 * 640 + g * 20;
    float s = 0.f, sq = 0.f;
    for (int idx = threadIdx.x; idx < 32 * 32 * 20; idx += 256) {
        int hw = idx / 20, c = idx - hw * 20;
        float v = base[(long)hw * 640 + c];
        s += v; sq += v * v;
    }
    __shared__ float rs[256], rq[256];
    rs[threadIdx.x] = s; rq[threadIdx.x] = sq; __syncthreads();
    for (int t = 128; t > 0; t >>= 1) {
        if (threadIdx.x < t) { rs[threadIdx.x] += rs[threadIdx.x + t]; rq[threadIdx.x] += rq[threadIdx.x + t]; }
        __syncthreads();
    }
    if (threadIdx.x == 0) {
        float mean = rs[0] / 20480.0f;
        float var = rq[0] / 20480.0f - mean * mean;
        stats[bid * 2] = mean;
        stats[bid * 2 + 1] = rsqrtf(var + 1e-5f);
    }
}

__global__ void gn_apply(const float* __restrict__ x, const float* __restrict__ stats,
                         const float* __restrict__ gamma, const float* __restrict__ beta,
                         u16* __restrict__ out) {
    long i = (long)blockIdx.x * 256 + threadIdx.x;
    int c = (int)(i % 640);
    int b = (int)(i / (32 * 32 * 640));
    int g = c / 20;
    float mean = stats[(b * 32 + g) * 2], inv = stats[(b * 32 + g) * 2 + 1];
    out[i] = f2b((x[i] - mean) * inv * gamma[c] + beta[c]);
}

// ---------------------------------------------------------------------------
__global__ void layernorm_rows(const float* __restrict__ X, const float* __restrict__ g,
                               const float* __restrict__ be, u16* __restrict__ out, int nrows) {
    int row = blockIdx.x * 4 + (threadIdx.x >> 6);
    int lane = threadIdx.x & 63;
    if (row >= nrows) return;
    const float* x = X + (long)row * 640;
    float v[10];
    float s = 0.f;
#pragma unroll
    for (int i = 0; i < 10; i++) { v[i] = x[lane + i * 64]; s += v[i]; }
#pragma unroll
    for (int m = 1; m < 64; m <<= 1) s += __shfl_xor(s, m);
    float mean = s * (1.0f / 640.0f);
    float sq = 0.f;
#pragma unroll
    for (int i = 0; i < 10; i++) { float d = v[i] - mean; sq += d * d; }
#pragma unroll
    for (int m = 1; m < 64; m <<= 1) sq += __shfl_xor(sq, m);
    float inv = rsqrtf(sq * (1.0f / 640.0f) + 1e-5f);
    u16* o = out + (long)row * 640;
#pragma unroll
    for (int i = 0; i < 10; i++) {
        int c = lane + i * 64;
        o[c] = f2b((v[i] - mean) * inv * g[c] + be[c]);
    }
}

// ---------------------------------------------------------------------------
__global__ void f2b_k(const float* __restrict__ src, u16* __restrict__ dst, long n) {
    long i = (long)blockIdx.x * 256 + threadIdx.x;
    if (i < n) dst[i] = f2b(src[i]);
}

// ===========================================================================
extern "C" void kernel_launch(void* const* d_in, const int* in_sizes, int n_in,
                              void* d_out, int out_size, void* d_ws, size_t ws_size,
                              hipStream_t stream) {
    const float* x        = (const float*)d_in[0];
    const float* context  = (const float*)d_in[1];
    const float* gn_gamma = (const float*)d_in[2];
    const float* gn_beta  = (const float*)d_in[3];
    const float* proj_in_w = (const float*)d_in[4];
    const float* proj_in_b = (const float*)d_in[5];
    const float* ln1_g = (const float*)d_in[6];
    const float* ln1_b = (const float*)d_in[7];
    const float* a1_q = (const float*)d_in[8];
    const float* a1_k = (const float*)d_in[9];
    const float* a1_v = (const float*)d_in[10];
    const float* a1_o = (const float*)d_in[11];
    const float* a1_ob = (const float*)d_in[12];
    const float* ln2_g = (const float*)d_in[13];
    const float* ln2_b = (const float*)d_in[14];
    const float* a2_q = (const float*)d_in[15];
    const float* a2_k = (const float*)d_in[16];
    const float* a2_v = (const float*)d_in[17];
    const float* a2_o = (const float*)d_in[18];
    const float* a2_ob = (const float*)d_in[19];
    const float* ln3_g = (const float*)d_in[20];
    const float* ln3_b = (const float*)d_in[21];
    const float* ff1_w = (const float*)d_in[22];
    const float* ff1_b = (const float*)d_in[23];
    const float* ff2_w = (const float*)d_in[24];
    const float* ff2_b = (const float*)d_in[25];
    const float* proj_out_w = (const float*)d_in[26];
    const float* proj_out_b = (const float*)d_in[27];
    float* out = (float*)d_out;

    // ---- workspace carve-up ----
    char* ws = (char*)d_ws;
    size_t off = 0;
    auto alloc = [&](size_t bytes) -> void* {
        void* p = ws + off;
        off += (bytes + 255) & ~(size_t)255;
        return p;
    };
    u16* Wt_pi  = (u16*)alloc(640 * 640 * 2);
    u16* Wt_qkv = (u16*)alloc((size_t)1920 * 640 * 2);
    u16* Wt_1o  = (u16*)alloc(640 * 640 * 2);
    u16* Wt_2q  = (u16*)alloc(640 * 640 * 2);
    u16* Wt_kv2 = (u16*)alloc((size_t)1280 * 768 * 2);
    u16* Wt_2o  = (u16*)alloc(640 * 640 * 2);
    u16* Wt_f1  = (u16*)alloc((size_t)5120 * 640 * 2);
    u16* Wt_f2  = (u16*)alloc((size_t)640 * 2560 * 2);
    u16* Wt_po  = (u16*)alloc(640 * 640 * 2);
    float* t    = (float*)alloc((size_t)8192 * 640 * 4);
    u16* bufA   = (u16*)alloc((size_t)8192 * 640 * 2);
    u16* big    = (u16*)alloc((size_t)8192 * 2560 * 2);  // qkv (8192x1920) / h (8192x2560)
    u16* kv2b   = (u16*)alloc((size_t)616 * 1280 * 2);
    u16* ctxb   = (u16*)alloc((size_t)616 * 768 * 2);
    float* stats = (float*)alloc(256 * 2 * 4);
    (void)alloc(131072);   // guard region: OOB M-tile DMA reads land here
    u16* qkvb = big;
    u16* hb   = big;

    const float SCALE = 0.11180339887498949f;

    auto gemm1 = [&](const u16* A, const u16* Bt, const float* bias,
                     const float* res, float* Cf, u16* Cb, int M, int N, int K,
                     int lda, int ldb, int ldc, float alpha, int mt) {
        GemmP p{};
        p.A = A; p.B = Bt; p.bias = bias; p.res = res; p.Cf = Cf; p.Cb = Cb;
        p.M = M; p.N = N; p.K = K; p.lda = lda; p.ldb = ldb; p.ldc = ldc;
        p.alpha = alpha;
        dim3 grid((N + 127) / 128, (M + mt - 1) / mt, 1);
        if (mt == 64) gemm_bt<64><<<grid, 256, 0, stream>>>(p);
        else          gemm_bt<128><<<grid, 256, 0, stream>>>(p);
    };

    // ---- 1. weight conversion ----
    {
        dim3 blk(32, 8);
        WT8 sq{};
        sq.W[0] = proj_in_w; sq.Wt[0] = Wt_pi;
        sq.W[1] = a1_q;      sq.Wt[1] = Wt_qkv;
        sq.W[2] = a1_k;      sq.Wt[2] = Wt_qkv + 640 * 640;
        sq.W[3] = a1_v;      sq.Wt[3] = Wt_qkv + 2 * 640 * 640;
        sq.W[4] = a1_o;      sq.Wt[4] = Wt_1o;
        sq.W[5] = a2_q;      sq.Wt[5] = Wt_2q;
        sq.W[6] = a2_o;      sq.Wt[6] = Wt_2o;
        sq.W[7] = proj_out_w; sq.Wt[7] = Wt_po;
        wtrans8<<<dim3(20, 20, 8), blk, 0, stream>>>(sq, 640, 640);
        WT8 kv{};
        kv.W[0] = a2_k; kv.Wt[0] = Wt_kv2;
        kv.W[1] = a2_v; kv.Wt[1] = Wt_kv2 + (size_t)640 * 768;
        wtrans8<<<dim3(20, 24, 2), blk, 0, stream>>>(kv, 768, 640);
        WT8 f1{}; f1.W[0] = ff1_w; f1.Wt[0] = Wt_f1;
        wtrans8<<<dim3(160, 20, 1), blk, 0, stream>>>(f1, 640, 5120);
        WT8 f2{}; f2.W[0] = ff2_w; f2.Wt[0] = Wt_f2;
        wtrans8<<<dim3(20, 80, 1), blk, 0, stream>>>(f2, 2560, 640);
    }

    // ---- 2. GroupNorm + proj_in ----
    gn_stats<<<256, 256, 0, stream>>>(x, stats);
    gn_apply<<<20480, 256, 0, stream>>>(x, stats, gn_gamma, gn_beta, bufA);
    gemm1(bufA, Wt_pi, proj_in_b, nullptr, t, nullptr, 8192, 640, 640, 640, 640, 640, 1.0f, 64);

    // ---- 3. self-attention ----
    layernorm_rows<<<2048, 256, 0, stream>>>(t, ln1_g, ln1_b, bufA, 8192);
    gemm1(bufA, Wt_qkv, nullptr, nullptr, nullptr, qkvb, 8192, 1920, 640, 640, 640, 1920, 1.0f, 64);
    {
        FlashP p{};
        p.Q = qkvb; p.K = qkvb + 640; p.V = qkvb + 1280; p.O = bufA;
        p.ldq = 1920; p.ldk = 1920; p.ldv = 1920; p.ldo = 640;
        p.S = 1024; p.TS = 1024; p.nIter = 8;
        p.qBatch = (long)1024 * 1920; p.kBatch = (long)1024 * 1920;
        p.scale = SCALE;
        flash_attn<<<dim3(64, 1, 8), 256, 0, stream>>>(p);
    }
    gemm1(bufA, Wt_1o, a1_ob, t, t, nullptr, 8192, 640, 640, 640, 640, 640, 1.0f, 64);

    // ---- 4. cross-attention ----
    layernorm_rows<<<2048, 256, 0, stream>>>(t, ln2_g, ln2_b, bufA, 8192);
    f2b_k<<<1848, 256, 0, stream>>>(context, ctxb, 473088);
    gemm1(bufA, Wt_2q, nullptr, nullptr, nullptr, qkvb, 8192, 640, 640, 640, 640, 640, 1.0f, 64);
    gemm1(ctxb, Wt_kv2, nullptr, nullptr, nullptr, kv2b, 616, 1280, 768, 768, 768, 1280, 1.0f, 64);
    {
        FlashP p{};
        p.Q = qkvb; p.K = kv2b; p.V = kv2b + 640; p.O = bufA;
        p.ldq = 640; p.ldk = 1280; p.ldv = 1280; p.ldo = 640;
        p.S = 1024; p.TS = 77; p.nIter = 1;
        p.qBatch = (long)1024 * 640; p.kBatch = (long)77 * 1280;
        p.scale = SCALE;
        flash_attn<<<dim3(64, 1, 8), 256, 0, stream>>>(p);
    }
    gemm1(bufA, Wt_2o, a2_ob, t, t, nullptr, 8192, 640, 640, 640, 640, 640, 1.0f, 64);

    // ---- 5. FFN: fused ff1+GEGLU (XCD n-ownership grid), then ff2 ----
    layernorm_rows<<<2048, 256, 0, stream>>>(t, ln3_g, ln3_b, bufA, 8192);
    {
        GegluP p{};
        p.A = bufA; p.Bx = Wt_f1; p.Bg = Wt_f1 + (size_t)2560 * 640;
        p.bx = ff1_b; p.bg = ff1_b + 2560;
        p.H = hb;
        p.K = 640; p.lda = 640; p.ldb = 640; p.ldh = 2560;
        gemm_geglu<<<dim3(8, 64, 3), 256, 0, stream>>>(p);
    }
    gemm1(hb, Wt_f2, ff2_b, t, t, nullptr, 8192, 640, 2560, 2560, 2560, 640, 1.0f, 64);

    // ---- 6. proj_out + x residual ----
    f2b_k<<<20480, 256, 0, stream>>>(t, bufA, 5242880);
    gemm1(bufA, Wt_po, proj_out_b, x, out, nullptr, 8192, 640, 640, 640, 640, 640, 1.0f, 64);
}

// Round 8
// 709.723 us; speedup vs baseline: 1.0297x; 1.0297x over previous
//
#include <hip/hip_runtime.h>
#include <hip/hip_bf16.h>
#include <math.h>

typedef unsigned short u16;
typedef unsigned int u32;
typedef __attribute__((ext_vector_type(8))) short bf16x8;
typedef __attribute__((ext_vector_type(4))) float f32x4;

__device__ __forceinline__ u16 f2b(float f) {
    union { float f; unsigned u; } v; v.f = f;
    unsigned r = v.u + 0x7fffu + ((v.u >> 16) & 1u);
    return (u16)(r >> 16);
}
__device__ __forceinline__ float b2f(u16 h) {
    union { unsigned u; float f; } v; v.u = ((unsigned)h) << 16; return v.f;
}

// global -> LDS direct DMA, 16 bytes per lane. LDS dest = uniform base + lane*16.
__device__ __forceinline__ void gld16(const u16* gp, u16* lp) {
    auto g = (const __attribute__((address_space(1))) u32*)gp;
    auto l = (__attribute__((address_space(3))) u32*)lp;
    __builtin_amdgcn_global_load_lds(g, l, 16, 0, 0);
}

// Conflict-free layout (R4/R6-verified, 0 conflicts): subtile row = 32 u16 (64 B),
// four 16B blocks; physical block for logical block q at row r: (q+(r>>1))&3.
__device__ __forceinline__ int swz4(int row, int q) { return (q + (row >> 1)) & 3; }

// ---------------------------------------------------------------------------
// bf16 MFMA GEMM, double-buffered LDS, prefetch-past-barrier, BK=64.
// C = alpha * A @ Bt^T (+bias) (+res). A: MxK (lda), Bt: NxK (ldb), bf16.
// K % 64 == 0. N-tile 128. M-tile = MT. One barrier per K-step.
// OOB M rows DMA garbage from within ws (store-guarded); keep guard region.
// ---------------------------------------------------------------------------
struct GemmP {
    const u16* A; const u16* B;
    const float* bias; const float* res;
    float* Cf; u16* Cb;
    int M, N, K, lda, ldb, ldc;
    float alpha;
};

template<int MT>
__global__ __launch_bounds__(256) void gemm_bt(GemmP p) {
    constexpr int MI = MT / 32;
    __shared__ u16 As[2][MT * 64];    // [buf][sub(2)][MT][32]
    __shared__ u16 Bs[2][128 * 64];   // [buf][sub(2)][128][32]
    const int tid = threadIdx.x;
    const int m0 = blockIdx.y * MT, n0 = blockIdx.x * 128;
    const int lane = tid & 63, wave = tid >> 6;
    const int quad = lane >> 4, l16 = lane & 15;
    const int wr = (wave >> 1) * (MT / 2), wc = (wave & 1) * 64;
    const int srow4 = lane >> 2, pcb4 = lane & 3;

    f32x4 acc[MI][4];
#pragma unroll
    for (int i = 0; i < MI; i++)
#pragma unroll
        for (int j = 0; j < 4; j++) acc[i][j] = (f32x4){0.f, 0.f, 0.f, 0.f};

    auto stage = [&](int buf, int k0) {
#pragma unroll
        for (int c = 0; c < MT / 32; c++) {
            int cc = wave * (MT / 32) + c;
            int sub = cc / (MT / 16), rg = cc % (MT / 16);
            int r = rg * 16 + srow4;
            int lcb = (pcb4 - (r >> 1)) & 3;
            gld16(p.A + (long)(m0 + r) * p.lda + k0 + sub * 32 + lcb * 8,
                  &As[buf][sub * (MT * 32) + rg * 512]);
        }
#pragma unroll
        for (int c = 0; c < 4; c++) {
            int cc = wave * 4 + c;
            int sub = cc >> 3, rg = cc & 7;
            int r = rg * 16 + srow4;
            int lcb = (pcb4 - (r >> 1)) & 3;
            gld16(p.B + (long)(n0 + r) * p.ldb + k0 + sub * 32 + lcb * 8,
                  &Bs[buf][sub * 4096 + rg * 512]);
        }
    };

    const int nIter = p.K >> 6;
    stage(0, 0);
    int buf = 0;
    for (int it = 0; it < nIter; it++) {
        __syncthreads();
        if (it + 1 < nIter) stage(buf ^ 1, (it + 1) << 6);
#pragma unroll
        for (int sub = 0; sub < 2; sub++) {
            bf16x8 af[MI], bfr[4];
#pragma unroll
            for (int mi = 0; mi < MI; mi++) {
                int row = wr + mi * 16 + l16;
                af[mi] = *(const bf16x8*)&As[buf][sub * (MT * 32) + row * 32 + swz4(row, quad) * 8];
            }
#pragma unroll
            for (int ni = 0; ni < 4; ni++) {
                int row = wc + ni * 16 + l16;
                bfr[ni] = *(const bf16x8*)&Bs[buf][sub * 4096 + row * 32 + swz4(row, quad) * 8];
            }
#pragma unroll
            for (int mi = 0; mi < MI; mi++)
#pragma unroll
                for (int ni = 0; ni < 4; ni++)
                    acc[mi][ni] = __builtin_amdgcn_mfma_f32_16x16x32_bf16(af[mi], bfr[ni], acc[mi][ni], 0, 0, 0);
        }
        buf ^= 1;
    }

#pragma unroll
    for (int mi = 0; mi < MI; mi++) {
#pragma unroll
        for (int ni = 0; ni < 4; ni++) {
#pragma unroll
            for (int r = 0; r < 4; r++) {
                int row = m0 + wr + mi * 16 + quad * 4 + r;
                int col = n0 + wc + ni * 16 + l16;
                if (row < p.M && col < p.N) {
                    float v = acc[mi][ni][r] * p.alpha;
                    if (p.bias) v += p.bias[col];
                    long idx = (long)row * p.ldc + col;
                    if (p.res) v += p.res[idx];
                    if (p.Cf) p.Cf[idx] = v; else p.Cb[idx] = f2b(v);
                }
            }
        }
    }
}

// ---------------------------------------------------------------------------
// Fused ff1 + GEGLU, double-buffered BK=32, prefetch-past-barrier.
// Plain grid (2560/128, M/128) — R6 config, measured 121 us / FETCH 69 MB.
// ---------------------------------------------------------------------------
struct GegluP {
    const u16* A; const u16* Bx; const u16* Bg;
    const float* bx; const float* bg;
    u16* H;
    int K, lda, ldb, ldh;
};

__global__ __launch_bounds__(256) void gemm_geglu(GegluP p) {
    __shared__ u16 As[2][128 * 32];
    __shared__ u16 Bxs[2][128 * 32];
    __shared__ u16 Bgs[2][128 * 32];
    const int tid = threadIdx.x;
    const int m0 = blockIdx.y * 128, n0 = blockIdx.x * 128;
    const int lane = tid & 63, wave = tid >> 6;
    const int quad = lane >> 4, l16 = lane & 15;
    const int wr = (wave >> 1) * 64, wc = (wave & 1) * 64;
    const int srow4 = lane >> 2, pcb4 = lane & 3;

    f32x4 ax[4][4], ag[4][4];
#pragma unroll
    for (int i = 0; i < 4; i++)
#pragma unroll
        for (int j = 0; j < 4; j++) { ax[i][j] = (f32x4){0.f,0.f,0.f,0.f}; ag[i][j] = (f32x4){0.f,0.f,0.f,0.f}; }

    auto stage = [&](int buf, int k0) {
#pragma unroll
        for (int c = 0; c < 2; c++) {
            int rg = wave * 2 + c;
            int r = rg * 16 + srow4;
            int lcb = (pcb4 - (r >> 1)) & 3;
            gld16(p.A  + (long)(m0 + r) * p.lda + k0 + lcb * 8, &As[buf][rg * 512]);
            gld16(p.Bx + (long)(n0 + r) * p.ldb + k0 + lcb * 8, &Bxs[buf][rg * 512]);
            gld16(p.Bg + (long)(n0 + r) * p.ldb + k0 + lcb * 8, &Bgs[buf][rg * 512]);
        }
    };

    const int nIter = p.K >> 5;
    stage(0, 0);
    int buf = 0;
    for (int it = 0; it < nIter; it++) {
        __syncthreads();
        if (it + 1 < nIter) stage(buf ^ 1, (it + 1) << 5);
        bf16x8 af[4], bxf[4], bgf[4];
#pragma unroll
        for (int mi = 0; mi < 4; mi++) {
            int row = wr + mi * 16 + l16;
            af[mi] = *(const bf16x8*)&As[buf][row * 32 + swz4(row, quad) * 8];
        }
#pragma unroll
        for (int ni = 0; ni < 4; ni++) {
            int row = wc + ni * 16 + l16;
            bxf[ni] = *(const bf16x8*)&Bxs[buf][row * 32 + swz4(row, quad) * 8];
            bgf[ni] = *(const bf16x8*)&Bgs[buf][row * 32 + swz4(row, quad) * 8];
        }
#pragma unroll
        for (int mi = 0; mi < 4; mi++)
#pragma unroll
            for (int ni = 0; ni < 4; ni++) {
                ax[mi][ni] = __builtin_amdgcn_mfma_f32_16x16x32_bf16(af[mi], bxf[ni], ax[mi][ni], 0, 0, 0);
                ag[mi][ni] = __builtin_amdgcn_mfma_f32_16x16x32_bf16(af[mi], bgf[ni], ag[mi][ni], 0, 0, 0);
            }
        buf ^= 1;
    }

#pragma unroll
    for (int mi = 0; mi < 4; mi++) {
#pragma unroll
        for (int ni = 0; ni < 4; ni++) {
#pragma unroll
            for (int r = 0; r < 4; r++) {
                int row = m0 + wr + mi * 16 + quad * 4 + r;
                int col = wc + ni * 16 + l16;
                float xh = ax[mi][ni][r] + p.bx[n0 + col];
                float g  = ag[mi][ni][r] + p.bg[n0 + col];
                float u  = 0.7978845608f * g * (1.0f + 0.044715f * g * g);
                float s  = 1.0f / (1.0f + __expf(-2.0f * u));
                p.H[(long)row * p.ldh + n0 + col] = f2b(xh * g * s);
            }
        }
    }
}

// ---------------------------------------------------------------------------
// Fused flash attention. Grid: (64 heads, 1, nQtiles); blockIdx.x = z = b*8+h
// -> q-tile blocks of one head share an XCD -> K/V served from that XCD's L2.
// Scale folded into Q at staging; full K-tiles take the maskless fast path.
// ---------------------------------------------------------------------------
struct FlashP {
    const u16* Q; const u16* K; const u16* V;
    u16* O;
    int ldq, ldk, ldv, ldo;
    int S, TS, nIter;
    long qBatch, kBatch;
    float scale;
};

__global__ __launch_bounds__(256, 2) void flash_attn(FlashP p) {
    __shared__ u16 shU[128 * 136];
    __shared__ u16 shV[80 * 136];
    const int z = blockIdx.x, b = z >> 3, h = z & 7;
    const int q0 = blockIdx.z * 128;
    const int tid = threadIdx.x, lane = tid & 63, w = tid >> 6;
    const int quad = lane >> 4, l16 = lane & 15;

    const u16* Qp = p.Q + (long)b * p.qBatch + (long)q0 * p.ldq + h * 80;
    const u16* Kp = p.K + (long)b * p.kBatch + h * 80;
    const u16* Vp = p.V + (long)b * p.kBatch + h * 80;

    for (int idx = tid; idx < 128 * 12; idx += 256) {
        int row = idx / 12, g = idx - row * 12;
        uint4 v = {0, 0, 0, 0};
        if (g < 10) {
            v = *(const uint4*)(Qp + (long)row * p.ldq + g * 8);
            u16 tmp[8]; *(uint4*)tmp = v;
#pragma unroll
            for (int j = 0; j < 8; j++) tmp[j] = f2b(b2f(tmp[j]) * p.scale);
            v = *(uint4*)tmp;
        }
        *(uint4*)&shU[row * 104 + g * 8] = v;
    }
    __syncthreads();
    bf16x8 qf[2][3];
#pragma unroll
    for (int mi = 0; mi < 2; mi++)
#pragma unroll
        for (int kk = 0; kk < 3; kk++)
            qf[mi][kk] = *(const bf16x8*)&shU[(w * 32 + mi * 16 + l16) * 104 + kk * 32 + quad * 8];
    __syncthreads();

    float m_[2][4], l_[2][4];
    f32x4 acc_o[2][5];
#pragma unroll
    for (int mi = 0; mi < 2; mi++) {
#pragma unroll
        for (int r = 0; r < 4; r++) { m_[mi][r] = -1e30f; l_[mi][r] = 0.f; }
#pragma unroll
        for (int ni = 0; ni < 5; ni++) acc_o[mi][ni] = (f32x4){0.f, 0.f, 0.f, 0.f};
    }

    for (int it = 0; it < p.nIter; it++) {
        const int s0 = it * 128;
        const bool full = (s0 + 128 <= p.TS);
        for (int idx = tid; idx < 128 * 12; idx += 256) {
            int row = idx / 12, g = idx - row * 12;
            uint4 v = {0, 0, 0, 0};
            if (g < 10 && (s0 + row) < p.TS)
                v = *(const uint4*)(Kp + (long)(s0 + row) * p.ldk + g * 8);
            *(uint4*)&shU[row * 104 + g * 8] = v;
        }
        for (int idx = tid; idx < 128 * 10; idx += 256) {
            int row = idx / 10, g = idx - row * 10;
            uint4 v = {0, 0, 0, 0};
            if ((s0 + row) < p.TS)
                v = *(const uint4*)(Vp + (long)(s0 + row) * p.ldv + g * 8);
            u16 tmp[8]; *(uint4*)tmp = v;
#pragma unroll
            for (int j = 0; j < 8; j++) shV[(g * 8 + j) * 136 + row] = tmp[j];
        }
        __syncthreads();

        f32x4 acc_s[2][8];
#pragma unroll
        for (int mi = 0; mi < 2; mi++)
#pragma unroll
            for (int ni = 0; ni < 8; ni++) acc_s[mi][ni] = (f32x4){0.f, 0.f, 0.f, 0.f};
#pragma unroll
        for (int kk = 0; kk < 3; kk++) {
            bf16x8 kf[8];
#pragma unroll
            for (int ni = 0; ni < 8; ni++)
                kf[ni] = *(const bf16x8*)&shU[(ni * 16 + l16) * 104 + kk * 32 + quad * 8];
#pragma unroll
            for (int mi = 0; mi < 2; mi++)
#pragma unroll
                for (int ni = 0; ni < 8; ni++)
                    acc_s[mi][ni] = __builtin_amdgcn_mfma_f32_16x16x32_bf16(qf[mi][kk], kf[ni], acc_s[mi][ni], 0, 0, 0);
        }
        __syncthreads();

        if (!full) {
#pragma unroll
            for (int mi = 0; mi < 2; mi++)
#pragma unroll
                for (int ni = 0; ni < 8; ni++) {
                    bool valid = (s0 + ni * 16 + l16) < p.TS;
#pragma unroll
                    for (int r = 0; r < 4; r++)
                        if (!valid) acc_s[mi][ni][r] = -1e30f;
                }
        }
#pragma unroll
        for (int mi = 0; mi < 2; mi++) {
#pragma unroll
            for (int r = 0; r < 4; r++) {
                float rm = acc_s[mi][0][r];
#pragma unroll
                for (int ni = 1; ni < 8; ni++) rm = fmaxf(rm, acc_s[mi][ni][r]);
#pragma unroll
                for (int msk = 1; msk < 16; msk <<= 1) rm = fmaxf(rm, __shfl_xor(rm, msk));
                float mn = fmaxf(m_[mi][r], rm);
                float al = __expf(m_[mi][r] - mn);
                m_[mi][r] = mn;
                float rs = 0.f;
                int prow = (w * 32 + mi * 16 + quad * 4 + r) * 136;
#pragma unroll
                for (int ni = 0; ni < 8; ni++) {
                    float pv = __expf(acc_s[mi][ni][r] - mn);
                    rs += pv;
                    shU[prow + ni * 16 + l16] = f2b(pv);
                }
#pragma unroll
                for (int msk = 1; msk < 16; msk <<= 1) rs += __shfl_xor(rs, msk);
                l_[mi][r] = l_[mi][r] * al + rs;
#pragma unroll
                for (int ni = 0; ni < 5; ni++) acc_o[mi][ni][r] *= al;
            }
        }
        __syncthreads();

#pragma unroll
        for (int kk = 0; kk < 4; kk++) {
            bf16x8 vf[5], pf[2];
#pragma unroll
            for (int ni = 0; ni < 5; ni++)
                vf[ni] = *(const bf16x8*)&shV[(ni * 16 + l16) * 136 + kk * 32 + quad * 8];
#pragma unroll
            for (int mi = 0; mi < 2; mi++)
                pf[mi] = *(const bf16x8*)&shU[(w * 32 + mi * 16 + l16) * 136 + kk * 32 + quad * 8];
#pragma unroll
            for (int mi = 0; mi < 2; mi++)
#pragma unroll
                for (int ni = 0; ni < 5; ni++)
                    acc_o[mi][ni] = __builtin_amdgcn_mfma_f32_16x16x32_bf16(pf[mi], vf[ni], acc_o[mi][ni], 0, 0, 0);
        }
        __syncthreads();
    }

    u16* Op = p.O + ((long)b * p.S + q0) * p.ldo + h * 80;
#pragma unroll
    for (int mi = 0; mi < 2; mi++) {
#pragma unroll
        for (int r = 0; r < 4; r++) {
            float inv = 1.0f / l_[mi][r];
            int row = w * 32 + mi * 16 + quad * 4 + r;
#pragma unroll
            for (int ni = 0; ni < 5; ni++)
                Op[(long)row * p.ldo + ni * 16 + l16] = f2b(acc_o[mi][ni][r] * inv);
        }
    }
}

// ---------------------------------------------------------------------------
struct WT8 { const float* W[8]; u16* Wt[8]; };

__global__ void wtrans8(WT8 p, int K, int N) {
    __shared__ float tile[32][33];
    const float* W = p.W[blockIdx.z];
    u16* Wt = p.Wt[blockIdx.z];
    int n0 = blockIdx.x * 32, k0 = blockIdx.y * 32;
    int tx = threadIdx.x, ty = threadIdx.y;
#pragma unroll
    for (int i = 0; i < 4; i++) {
        int k = k0 + ty + i * 8, n = n0 + tx;
        if (k < K && n < N) tile[ty + i * 8][tx] = W[(long)k * N + n];
    }
    __syncthreads();
#pragma unroll
    for (int i = 0; i < 4; i++) {
        int n = n0 + ty + i * 8, k = k0 + tx;
        if (n < N && k < K) Wt[(long)n * K + k] = f2b(tile[tx][ty + i * 8]);
    }
}

// ---------------------------------------------------------------------------
__global__ void gn_stats(const float* __restrict__ x, float* __restrict__ stats) {
    int bid = blockIdx.x;
    int b = bid >> 5, g = bid & 31;
    const float* base = x + (long)b * 32 * 32 * 640 + g * 20;
    float s = 0.f, sq = 0.f;
    for (int idx = threadIdx.x; idx < 32 * 32 * 20; idx += 256) {
        int hw = idx / 20, c = idx - hw * 20;
        float v = base[(long)hw * 640 + c];
        s += v; sq += v * v;
    }
    __shared__ float rs[256], rq[256];
    rs[threadIdx.x] = s; rq[threadIdx.x] = sq; __syncthreads();
    for (int t = 128; t > 0; t >>= 1) {
        if (threadIdx.x < t) { rs[threadIdx.x] += rs[threadIdx.x + t]; rq[threadIdx.x] += rq[threadIdx.x + t]; }
        __syncthreads();
    }
    if (threadIdx.x == 0) {
        float mean = rs[0] / 20480.0f;
        float var = rq[0] / 20480.0f - mean * mean;
        stats[bid * 2] = mean;
        stats[bid * 2 + 1] = rsqrtf(var + 1e-5f);
    }
}

__global__ void gn_apply(const float* __restrict__ x, const float* __restrict__ stats,
                         const float* __restrict__ gamma, const float* __restrict__ beta,
                         u16* __restrict__ out) {
    long i = (long)blockIdx.x * 256 + threadIdx.x;
    int c = (int)(i % 640);
    int b = (int)(i / (32 * 32 * 640));
    int g = c / 20;
    float mean = stats[(b * 32 + g) * 2], inv = stats[(b * 32 + g) * 2 + 1];
    out[i] = f2b((x[i] - mean) * inv * gamma[c] + beta[c]);
}

// ---------------------------------------------------------------------------
__global__ void layernorm_rows(const float* __restrict__ X, const float* __restrict__ g,
                               const float* __restrict__ be, u16* __restrict__ out, int nrows) {
    int row = blockIdx.x * 4 + (threadIdx.x >> 6);
    int lane = threadIdx.x & 63;
    if (row >= nrows) return;
    const float* x = X + (long)row * 640;
    float v[10];
    float s = 0.f;
#pragma unroll
    for (int i = 0; i < 10; i++) { v[i] = x[lane + i * 64]; s += v[i]; }
#pragma unroll
    for (int m = 1; m < 64; m <<= 1) s += __shfl_xor(s, m);
    float mean = s * (1.0f / 640.0f);
    float sq = 0.f;
#pragma unroll
    for (int i = 0; i < 10; i++) { float d = v[i] - mean; sq += d * d; }
#pragma unroll
    for (int m = 1; m < 64; m <<= 1) sq += __shfl_xor(sq, m);
    float inv = rsqrtf(sq * (1.0f / 640.0f) + 1e-5f);
    u16* o = out + (long)row * 640;
#pragma unroll
    for (int i = 0; i < 10; i++) {
        int c = lane + i * 64;
        o[c] = f2b((v[i] - mean) * inv * g[c] + be[c]);
    }
}

// ---------------------------------------------------------------------------
__global__ void f2b_k(const float* __restrict__ src, u16* __restrict__ dst, long n) {
    long i = (long)blockIdx.x * 256 + threadIdx.x;
    if (i < n) dst[i] = f2b(src[i]);
}

// ===========================================================================
extern "C" void kernel_launch(void* const* d_in, const int* in_sizes, int n_in,
                              void* d_out, int out_size, void* d_ws, size_t ws_size,
                              hipStream_t stream) {
    const float* x        = (const float*)d_in[0];
    const float* context  = (const float*)d_in[1];
    const float* gn_gamma = (const float*)d_in[2];
    const float* gn_beta  = (const float*)d_in[3];
    const float* proj_in_w = (const float*)d_in[4];
    const float* proj_in_b = (const float*)d_in[5];
    const float* ln1_g = (const float*)d_in[6];
    const float* ln1_b = (const float*)d_in[7];
    const float* a1_q = (const float*)d_in[8];
    const float* a1_k = (const float*)d_in[9];
    const float* a1_v = (const float*)d_in[10];
    const float* a1_o = (const float*)d_in[11];
    const float* a1_ob = (const float*)d_in[12];
    const float* ln2_g = (const float*)d_in[13];
    const float* ln2_b = (const float*)d_in[14];
    const float* a2_q = (const float*)d_in[15];
    const float* a2_k = (const float*)d_in[16];
    const float* a2_v = (const float*)d_in[17];
    const float* a2_o = (const float*)d_in[18];
    const float* a2_ob = (const float*)d_in[19];
    const float* ln3_g = (const float*)d_in[20];
    const float* ln3_b = (const float*)d_in[21];
    const float* ff1_w = (const float*)d_in[22];
    const float* ff1_b = (const float*)d_in[23];
    const float* ff2_w = (const float*)d_in[24];
    const float* ff2_b = (const float*)d_in[25];
    const float* proj_out_w = (const float*)d_in[26];
    const float* proj_out_b = (const float*)d_in[27];
    float* out = (float*)d_out;

    // ---- workspace carve-up ----
    char* ws = (char*)d_ws;
    size_t off = 0;
    auto alloc = [&](size_t bytes) -> void* {
        void* p = ws + off;
        off += (bytes + 255) & ~(size_t)255;
        return p;
    };
    u16* Wt_pi  = (u16*)alloc(640 * 640 * 2);
    u16* Wt_qkv = (u16*)alloc((size_t)1920 * 640 * 2);
    u16* Wt_1o  = (u16*)alloc(640 * 640 * 2);
    u16* Wt_2q  = (u16*)alloc(640 * 640 * 2);
    u16* Wt_kv2 = (u16*)alloc((size_t)1280 * 768 * 2);
    u16* Wt_2o  = (u16*)alloc(640 * 640 * 2);
    u16* Wt_f1  = (u16*)alloc((size_t)5120 * 640 * 2);
    u16* Wt_f2  = (u16*)alloc((size_t)640 * 2560 * 2);
    u16* Wt_po  = (u16*)alloc(640 * 640 * 2);
    float* t    = (float*)alloc((size_t)8192 * 640 * 4);
    u16* bufA   = (u16*)alloc((size_t)8192 * 640 * 2);
    u16* big    = (u16*)alloc((size_t)8192 * 2560 * 2);  // qkv (8192x1920) / h (8192x2560)
    u16* kv2b   = (u16*)alloc((size_t)616 * 1280 * 2);
    u16* ctxb   = (u16*)alloc((size_t)616 * 768 * 2);
    float* stats = (float*)alloc(256 * 2 * 4);
    (void)alloc(131072);   // guard region: OOB M-tile DMA reads land here
    u16* qkvb = big;
    u16* hb   = big;

    const float SCALE = 0.11180339887498949f;

    auto gemm1 = [&](const u16* A, const u16* Bt, const float* bias,
                     const float* res, float* Cf, u16* Cb, int M, int N, int K,
                     int lda, int ldb, int ldc, float alpha, int mt) {
        GemmP p{};
        p.A = A; p.B = Bt; p.bias = bias; p.res = res; p.Cf = Cf; p.Cb = Cb;
        p.M = M; p.N = N; p.K = K; p.lda = lda; p.ldb = ldb; p.ldc = ldc;
        p.alpha = alpha;
        dim3 grid((N + 127) / 128, (M + mt - 1) / mt, 1);
        if (mt == 64) gemm_bt<64><<<grid, 256, 0, stream>>>(p);
        else          gemm_bt<128><<<grid, 256, 0, stream>>>(p);
    };

    // ---- 1. weight conversion ----
    {
        dim3 blk(32, 8);
        WT8 sq{};
        sq.W[0] = proj_in_w; sq.Wt[0] = Wt_pi;
        sq.W[1] = a1_q;      sq.Wt[1] = Wt_qkv;
        sq.W[2] = a1_k;      sq.Wt[2] = Wt_qkv + 640 * 640;
        sq.W[3] = a1_v;      sq.Wt[3] = Wt_qkv + 2 * 640 * 640;
        sq.W[4] = a1_o;      sq.Wt[4] = Wt_1o;
        sq.W[5] = a2_q;      sq.Wt[5] = Wt_2q;
        sq.W[6] = a2_o;      sq.Wt[6] = Wt_2o;
        sq.W[7] = proj_out_w; sq.Wt[7] = Wt_po;
        wtrans8<<<dim3(20, 20, 8), blk, 0, stream>>>(sq, 640, 640);
        WT8 kv{};
        kv.W[0] = a2_k; kv.Wt[0] = Wt_kv2;
        kv.W[1] = a2_v; kv.Wt[1] = Wt_kv2 + (size_t)640 * 768;
        wtrans8<<<dim3(20, 24, 2), blk, 0, stream>>>(kv, 768, 640);
        WT8 f1{}; f1.W[0] = ff1_w; f1.Wt[0] = Wt_f1;
        wtrans8<<<dim3(160, 20, 1), blk, 0, stream>>>(f1, 640, 5120);
        WT8 f2{}; f2.W[0] = ff2_w; f2.Wt[0] = Wt_f2;
        wtrans8<<<dim3(20, 80, 1), blk, 0, stream>>>(f2, 2560, 640);
    }

    // ---- 2. GroupNorm + proj_in ----
    gn_stats<<<256, 256, 0, stream>>>(x, stats);
    gn_apply<<<20480, 256, 0, stream>>>(x, stats, gn_gamma, gn_beta, bufA);
    gemm1(bufA, Wt_pi, proj_in_b, nullptr, t, nullptr, 8192, 640, 640, 640, 640, 640, 1.0f, 64);

    // ---- 3. self-attention ----
    layernorm_rows<<<2048, 256, 0, stream>>>(t, ln1_g, ln1_b, bufA, 8192);
    gemm1(bufA, Wt_qkv, nullptr, nullptr, nullptr, qkvb, 8192, 1920, 640, 640, 640, 1920, 1.0f, 128);
    {
        FlashP p{};
        p.Q = qkvb; p.K = qkvb + 640; p.V = qkvb + 1280; p.O = bufA;
        p.ldq = 1920; p.ldk = 1920; p.ldv = 1920; p.ldo = 640;
        p.S = 1024; p.TS = 1024; p.nIter = 8;
        p.qBatch = (long)1024 * 1920; p.kBatch = (long)1024 * 1920;
        p.scale = SCALE;
        flash_attn<<<dim3(64, 1, 8), 256, 0, stream>>>(p);
    }
    gemm1(bufA, Wt_1o, a1_ob, t, t, nullptr, 8192, 640, 640, 640, 640, 640, 1.0f, 64);

    // ---- 4. cross-attention ----
    layernorm_rows<<<2048, 256, 0, stream>>>(t, ln2_g, ln2_b, bufA, 8192);
    f2b_k<<<1848, 256, 0, stream>>>(context, ctxb, 473088);
    gemm1(bufA, Wt_2q, nullptr, nullptr, nullptr, qkvb, 8192, 640, 640, 640, 640, 640, 1.0f, 64);
    gemm1(ctxb, Wt_kv2, nullptr, nullptr, nullptr, kv2b, 616, 1280, 768, 768, 768, 1280, 1.0f, 64);
    {
        FlashP p{};
        p.Q = qkvb; p.K = kv2b; p.V = kv2b + 640; p.O = bufA;
        p.ldq = 640; p.ldk = 1280; p.ldv = 1280; p.ldo = 640;
        p.S = 1024; p.TS = 77; p.nIter = 1;
        p.qBatch = (long)1024 * 640; p.kBatch = (long)77 * 1280;
        p.scale = SCALE;
        flash_attn<<<dim3(64, 1, 8), 256, 0, stream>>>(p);
    }
    gemm1(bufA, Wt_2o, a2_ob, t, t, nullptr, 8192, 640, 640, 640, 640, 640, 1.0f, 64);

    // ---- 5. FFN: fused ff1+GEGLU, then ff2 ----
    layernorm_rows<<<2048, 256, 0, stream>>>(t, ln3_g, ln3_b, bufA, 8192);
    {
        GegluP p{};
        p.A = bufA; p.Bx = Wt_f1; p.Bg = Wt_f1 + (size_t)2560 * 640;
        p.bx = ff1_b; p.bg = ff1_b + 2560;
        p.H = hb;
        p.K = 640; p.lda = 640; p.ldb = 640; p.ldh = 2560;
        gemm_geglu<<<dim3(20, 64), 256, 0, stream>>>(p);
    }
    gemm1(hb, Wt_f2, ff2_b, t, t, nullptr, 8192, 640, 2560, 2560, 2560, 640, 1.0f, 64);

    // ---- 6. proj_out + x residual ----
    f2b_k<<<20480, 256, 0, stream>>>(t, bufA, 5242880);
    gemm1(bufA, Wt_po, proj_out_b, x, out, nullptr, 8192, 640, 640, 640, 640, 640, 1.0f, 64);
}